// Round 1
// baseline (296.186 us; speedup 1.0000x reference)
//
#include <hip/hip_runtime.h>
#include <hip/hip_bf16.h>
#include <cstdint>

#define NBATCH 512
#define NDIM   2048
#define NHEADS 16
#define NCPH   128

typedef __bf16 bf16x8 __attribute__((ext_vector_type(8)));
typedef float  f32x4  __attribute__((ext_vector_type(4)));

__device__ __forceinline__ unsigned short f2bf(float f) {
    uint32_t u = __builtin_bit_cast(uint32_t, f);
    u += 0x7FFFu + ((u >> 16) & 1u);   // round-to-nearest-even
    return (unsigned short)(u >> 16);
}

__device__ __forceinline__ void gl_lds16(const void* g, void* l) {
    __builtin_amdgcn_global_load_lds(
        (const __attribute__((address_space(1))) void*)g,
        (__attribute__((address_space(3))) void*)l,
        16, 0, 0);
}

// ---------------- convert f32 -> bf16 for W_qv, W_out, x ----------------
__global__ __launch_bounds__(256) void cvt_all(
    const float* __restrict__ wqv, const float* __restrict__ wout,
    const float* __restrict__ x,
    unsigned short* __restrict__ owqv, unsigned short* __restrict__ owout,
    unsigned short* __restrict__ ox)
{
    int t = blockIdx.x * 256 + threadIdx.x;   // one float4 per thread
    const int n1 = (2*NDIM*NDIM)/4;   // W_qv  : 2097152 float4
    const int n2 = (NDIM*NDIM)/4;     // W_out : 1048576
    // x: 262144 float4
    const float4* src; unsigned short* dst; int idx;
    if (t < n1)            { src = (const float4*)wqv;  dst = owqv;  idx = t; }
    else if (t < n1 + n2)  { src = (const float4*)wout; dst = owout; idx = t - n1; }
    else                   { src = (const float4*)x;    dst = ox;    idx = t - n1 - n2; }
    float4 v = src[idx];
    ushort4 o;
    o.x = f2bf(v.x); o.y = f2bf(v.y); o.z = f2bf(v.z); o.w = f2bf(v.w);
    *(ushort4*)(dst + (size_t)idx * 4) = o;
}

// ---------------- bf16 GEMM, C[m,n] = sum_k A[m,k]*B[n,k] (+bias[n]) ----
// A: M x K bf16 row-major, B: N x K bf16 row-major, C: M x N f32
// BM=64, BN=128, BK=32, 256 threads (4 waves, 2x2; each wave 32x64)
__global__ __launch_bounds__(256) void gemm_bt(
    const unsigned short* __restrict__ A, const unsigned short* __restrict__ B,
    float* __restrict__ C, const float* __restrict__ bias,
    int M, int N, int K)
{
    __shared__ unsigned short As[64 * 32];
    __shared__ unsigned short Bs[128 * 32];

    const int tid  = threadIdx.x;
    const int lane = tid & 63;
    const int wid  = tid >> 6;
    const int wr   = wid >> 1;    // 0..1
    const int wc   = wid & 1;     // 0..1
    const int m0   = blockIdx.y * 64;
    const int n0   = blockIdx.x * 128;

    f32x4 acc[2][4] = {};

    const int e    = tid * 8;          // element offset in staged tile
    const int arow = e >> 5;           // /32
    const int akk  = e & 31;

    const unsigned short* Ag  = A + (size_t)(m0 + arow) * K + akk;
    const unsigned short* Bg0 = B + (size_t)(n0 + arow) * K + akk;
    const unsigned short* Bg1 = B + (size_t)(n0 + 64 + arow) * K + akk;

    const int krow = (lane >> 4) * 8;  // k offset of this lane's fragment
    const int fr   = lane & 15;

    for (int k0 = 0; k0 < K; k0 += 32) {
        __syncthreads();
        gl_lds16(Ag  + k0, As + e);
        gl_lds16(Bg0 + k0, Bs + e);
        gl_lds16(Bg1 + k0, Bs + 2048 + e);
        __syncthreads();

        bf16x8 af[2], bfr[4];
#pragma unroll
        for (int i = 0; i < 2; i++)
            af[i] = *(const bf16x8*)(As + (wr * 32 + i * 16 + fr) * 32 + krow);
#pragma unroll
        for (int j = 0; j < 4; j++)
            bfr[j] = *(const bf16x8*)(Bs + (wc * 64 + j * 16 + fr) * 32 + krow);
#pragma unroll
        for (int i = 0; i < 2; i++)
#pragma unroll
            for (int j = 0; j < 4; j++)
                acc[i][j] = __builtin_amdgcn_mfma_f32_16x16x32_bf16(
                    af[i], bfr[j], acc[i][j], 0, 0, 0);
    }

    const int row0 = m0 + wr * 32 + ((lane >> 4) << 2);
    const int col0 = n0 + wc * 64 + fr;
#pragma unroll
    for (int j = 0; j < 4; j++) {
        const int cc = col0 + j * 16;
        const float badd = bias ? bias[cc] : 0.0f;
#pragma unroll
        for (int i = 0; i < 2; i++) {
            const int rr = row0 + i * 16;
#pragma unroll
            for (int r = 0; r < 4; r++)
                C[(size_t)(rr + r) * N + cc] = acc[i][j][r] + badd;
        }
    }
}

// ---------------- per-head batchnorm stats over v = qv[:, DIM:] --------
__global__ __launch_bounds__(256) void bn_stats(
    const float* __restrict__ qv, const float* __restrict__ gamma,
    const float* __restrict__ beta, float* __restrict__ hscale,
    float* __restrict__ hshift)
{
    const int h = blockIdx.x;
    const int tid = threadIdx.x;
    float s = 0.f, ss = 0.f;
    for (int t = tid; t < NBATCH * NCPH; t += 256) {
        const int b = t >> 7, c = t & 127;
        float v = qv[(size_t)b * (2 * NDIM) + NDIM + h * NCPH + c];
        s += v;
        ss = fmaf(v, v, ss);
    }
#pragma unroll
    for (int off = 32; off; off >>= 1) {
        s  += __shfl_down(s, off);
        ss += __shfl_down(ss, off);
    }
    __shared__ float ls[4], lss[4];
    const int wv = tid >> 6;
    if ((tid & 63) == 0) { ls[wv] = s; lss[wv] = ss; }
    __syncthreads();
    if (tid == 0) {
        float S  = ls[0] + ls[1] + ls[2] + ls[3];
        float SS = lss[0] + lss[1] + lss[2] + lss[3];
        const float inv = 1.0f / (NBATCH * NCPH);
        float mean = S * inv;
        float var  = SS * inv - mean * mean;
        float sc   = gamma[h] * rsqrtf(var + 1e-5f);
        hscale[h] = sc;
        hshift[h] = beta[h] - mean * sc;
    }
}

// ---------------- fused outer-product + bias + softmax + PV ------------
// one block per (b,h); 256 threads; thread pair (2c, 2c+1) owns row c
__global__ __launch_bounds__(256) void attn_k(
    const float* __restrict__ qv, const float* __restrict__ kparam,
    const float* __restrict__ bias, const float* __restrict__ temperature,
    const float* __restrict__ hscale, const float* __restrict__ hshift,
    unsigned short* __restrict__ aout)
{
    const int bh = blockIdx.x;
    const int b  = bh >> 4;
    const int h  = bh & 15;
    const int tid = threadIdx.x;

    __shared__ float ks[NCPH], vs[NCPH];
    if (tid < NCPH) {
        ks[tid] = kparam[(size_t)b * NDIM + h * NCPH + tid];
        vs[tid] = qv[(size_t)b * (2 * NDIM) + NDIM + h * NCPH + tid] * hscale[h]
                  + hshift[h];
    }
    const int c = tid >> 1, half = tid & 1;
    const float qc   = qv[(size_t)b * (2 * NDIM) + h * NCPH + c];
    const float temp = temperature[h];
    __syncthreads();

    const float4* bp = (const float4*)(bias + ((size_t)bh << 14)
                                       + (size_t)c * NCPH + half * 64);
    float4 l4[16];
#pragma unroll
    for (int j = 0; j < 16; j++) l4[j] = bp[j];
    float* l = (float*)l4;

    const float* kk = ks + half * 64;
    const float* vv = vs + half * 64;

    float m = -1e30f;
#pragma unroll
    for (int j = 0; j < 64; j++) {
        l[j] = fmaf(qc, kk[j], l[j]) * temp;
        m = fmaxf(m, l[j]);
    }
    m = fmaxf(m, __shfl_xor(m, 1));

    float s = 0.f, o = 0.f;
#pragma unroll
    for (int j = 0; j < 64; j++) {
        float p = __expf(l[j] - m);
        s += p;
        o = fmaf(p, vv[j], o);
    }
    s += __shfl_xor(s, 1);
    o += __shfl_xor(o, 1);

    if (half == 0)
        aout[(size_t)b * NDIM + h * NCPH + c] = f2bf(o / s);
}

// ------------------------------ launch ---------------------------------
extern "C" void kernel_launch(void* const* d_in, const int* in_sizes, int n_in,
                              void* d_out, int out_size, void* d_ws, size_t ws_size,
                              hipStream_t stream)
{
    const float* x      = (const float*)d_in[0];
    const float* Wqv    = (const float*)d_in[1];
    const float* temp   = (const float*)d_in[2];
    const float* kparam = (const float*)d_in[3];
    const float* bias   = (const float*)d_in[4];
    const float* gamma  = (const float*)d_in[5];
    const float* beta   = (const float*)d_in[6];
    const float* Wout   = (const float*)d_in[7];
    const float* bout   = (const float*)d_in[8];
    float* out = (float*)d_out;

    char* ws = (char*)d_ws;
    unsigned short* wqv_bf  = (unsigned short*)(ws);              // 16 MiB
    unsigned short* wout_bf = (unsigned short*)(ws + 16777216);   //  8 MiB
    unsigned short* x_bf    = (unsigned short*)(ws + 25165824);   //  2 MiB
    float*          qv      = (float*)(ws + 27262976);            //  8 MiB
    unsigned short* ao_bf   = (unsigned short*)(ws + 35651584);   //  2 MiB
    float*          hscale  = (float*)(ws + 37748736);
    float*          hshift  = (float*)(ws + 37748800);

    cvt_all<<<13312, 256, 0, stream>>>(Wqv, Wout, x, wqv_bf, wout_bf, x_bf);

    // qv = x @ W_qv^T : M=512, N=4096, K=2048
    gemm_bt<<<dim3(4096 / 128, 512 / 64), 256, 0, stream>>>(
        x_bf, wqv_bf, qv, nullptr, NBATCH, 2 * NDIM, NDIM);

    bn_stats<<<NHEADS, 256, 0, stream>>>(qv, gamma, beta, hscale, hshift);

    attn_k<<<NBATCH * NHEADS, 256, 0, stream>>>(
        qv, kparam, bias, temp, hscale, hshift, ao_bf);

    // out = attn_out @ W_out^T + b_out : M=512, N=2048, K=2048
    gemm_bt<<<dim3(2048 / 128, 512 / 64), 256, 0, stream>>>(
        ao_bf, wout_bf, out, bout, NBATCH, NDIM, NDIM);
}

// Round 2
// 206.532 us; speedup vs baseline: 1.4341x; 1.4341x over previous
//
#include <hip/hip_runtime.h>
#include <hip/hip_bf16.h>
#include <cstdint>

#define NBATCH 512
#define NDIM   2048
#define NHEADS 16
#define NCPH   128

typedef __bf16 bf16x8 __attribute__((ext_vector_type(8)));
typedef float  f32x4  __attribute__((ext_vector_type(4)));

__device__ __forceinline__ unsigned short f2bf(float f) {
    uint32_t u = __builtin_bit_cast(uint32_t, f);
    u += 0x7FFFu + ((u >> 16) & 1u);   // round-to-nearest-even
    return (unsigned short)(u >> 16);
}

__device__ __forceinline__ void gl_lds16(const void* g, void* l) {
    __builtin_amdgcn_global_load_lds(
        (const __attribute__((address_space(1))) void*)g,
        (__attribute__((address_space(3))) void*)l,
        16, 0, 0);
}

// ---------------- convert f32 -> bf16 for W_qv, W_out, x ----------------
__global__ __launch_bounds__(256) void cvt_all(
    const float* __restrict__ wqv, const float* __restrict__ wout,
    const float* __restrict__ x,
    unsigned short* __restrict__ owqv, unsigned short* __restrict__ owout,
    unsigned short* __restrict__ ox)
{
    int t = blockIdx.x * 256 + threadIdx.x;   // one float4 per thread
    const int n1 = (2*NDIM*NDIM)/4;   // W_qv  : 2097152 float4
    const int n2 = (NDIM*NDIM)/4;     // W_out : 1048576
    const float4* src; unsigned short* dst; int idx;
    if (t < n1)            { src = (const float4*)wqv;  dst = owqv;  idx = t; }
    else if (t < n1 + n2)  { src = (const float4*)wout; dst = owout; idx = t - n1; }
    else                   { src = (const float4*)x;    dst = ox;    idx = t - n1 - n2; }
    float4 v = src[idx];
    ushort4 o;
    o.x = f2bf(v.x); o.y = f2bf(v.y); o.z = f2bf(v.z); o.w = f2bf(v.w);
    *(ushort4*)(dst + (size_t)idx * 4) = o;
}

// ---------------- bf16 GEMM, C[m,n] = sum_k A[m,k]*B[n,k] (+bias[n]) ----
// A: M x K bf16 row-major, B: N x K bf16 row-major, C: M x N f32
// 256 threads = 4 waves in 2x2; wave computes (BM/2) x (BN/2).
// 2-phase pipeline: stage tile t+1 (global_load_lds, linear LDS dest with
// pre-swizzled global source), then ds_read+MFMA tile t, one barrier/step.
template<int BM, int BN, int BK>
__global__ __launch_bounds__(256) void gemm_bt(
    const unsigned short* __restrict__ A, const unsigned short* __restrict__ B,
    float* __restrict__ C, const float* __restrict__ bias,
    int M, int N, int K)
{
    constexpr int WM = BM / 2, WN = BN / 2;
    constexpr int MI = WM / 16, NI = WN / 16;
    constexpr int NTA = (BM * BK) / 2048;   // gl_lds16 rounds for A tile
    constexpr int NTB = (BN * BK) / 2048;

    __shared__ unsigned short As[2][BM * BK];
    __shared__ unsigned short Bs[2][BN * BK];

    const int tid  = threadIdx.x;
    const int lane = tid & 63;
    const int wid  = tid >> 6;
    const int wr   = wid >> 1;     // 0..1
    const int wc   = wid & 1;      // 0..1
    const int m0   = blockIdx.y * BM;
    const int n0   = blockIdx.x * BN;
    const int fr   = lane & 15;    // fragment row/col within 16
    const int kq   = lane >> 4;    // 0..3, k-quarter of 32-slice

    f32x4 acc[MI][NI] = {};

    auto stage = [&](int bs, int k0) {
#pragma unroll
        for (int r = 0; r < NTA; r++) {
            const int e    = r * 2048 + tid * 8;
            const int row  = e / BK;
            const int col  = ((((e & (BK - 1)) >> 3) ^ (row & 7)) << 3);
            gl_lds16(A + (size_t)(m0 + row) * K + k0 + col, &As[bs][e]);
        }
#pragma unroll
        for (int r = 0; r < NTB; r++) {
            const int e    = r * 2048 + tid * 8;
            const int row  = e / BK;
            const int col  = ((((e & (BK - 1)) >> 3) ^ (row & 7)) << 3);
            gl_lds16(B + (size_t)(n0 + row) * K + k0 + col, &Bs[bs][e]);
        }
    };

    auto compute = [&](int bs) {
#pragma unroll
        for (int kh = 0; kh < BK / 32; kh++) {
            const int kchunk = kh * 4 + kq;
            bf16x8 af[MI], bfv[NI];
#pragma unroll
            for (int i = 0; i < MI; i++) {
                const int row = wr * WM + i * 16 + fr;
                af[i] = *(const bf16x8*)&As[bs][row * BK + ((kchunk ^ (row & 7)) << 3)];
            }
#pragma unroll
            for (int j = 0; j < NI; j++) {
                const int row = wc * WN + j * 16 + fr;
                bfv[j] = *(const bf16x8*)&Bs[bs][row * BK + ((kchunk ^ (row & 7)) << 3)];
            }
#pragma unroll
            for (int i = 0; i < MI; i++)
#pragma unroll
                for (int j = 0; j < NI; j++)
                    acc[i][j] = __builtin_amdgcn_mfma_f32_16x16x32_bf16(
                        af[i], bfv[j], acc[i][j], 0, 0, 0);
        }
    };

    stage(0, 0);
    __syncthreads();

    const int NT = K / BK;
    int cur = 0;
    for (int t = 0; t < NT - 1; t++) {
        stage(cur ^ 1, (t + 1) * BK);   // prefetch next tile (overlaps compute)
        compute(cur);
        __syncthreads();                // drains vmcnt+lgkm: next tile ready
        cur ^= 1;
    }
    compute(cur);

    const int row0 = m0 + wr * WM + (kq << 2);
    const int col0 = n0 + wc * WN + fr;
#pragma unroll
    for (int j = 0; j < NI; j++) {
        const int cc = col0 + j * 16;
        const float badd = bias ? bias[cc] : 0.0f;
#pragma unroll
        for (int i = 0; i < MI; i++)
#pragma unroll
            for (int r = 0; r < 4; r++)
                C[(size_t)(row0 + i * 16 + r) * N + cc] = acc[i][j][r] + badd;
    }
}

// ---------------- per-head batchnorm partial sums over v ---------------
// 64 blocks: blockIdx = h*4 + quarter; each reduces 128 batches x 128 ch
__global__ __launch_bounds__(256) void bn_partial(
    const float* __restrict__ qv, float* __restrict__ part)
{
    const int h = blockIdx.x >> 2, q = blockIdx.x & 3;
    const int tid = threadIdx.x;
    float s = 0.f, ss = 0.f;
#pragma unroll
    for (int it = 0; it < 16; it++) {
        const int idx = it * 256 + tid;
        const int b   = q * 128 + (idx >> 5);
        const int c4  = idx & 31;
        float4 v = *(const float4*)&qv[(size_t)b * (2 * NDIM) + NDIM + h * NCPH + c4 * 4];
        s += v.x + v.y + v.z + v.w;
        ss = fmaf(v.x, v.x, fmaf(v.y, v.y, fmaf(v.z, v.z, fmaf(v.w, v.w, ss))));
    }
#pragma unroll
    for (int off = 32; off; off >>= 1) {
        s  += __shfl_down(s, off);
        ss += __shfl_down(ss, off);
    }
    __shared__ float ls[4], lss[4];
    if ((tid & 63) == 0) { ls[tid >> 6] = s; lss[tid >> 6] = ss; }
    __syncthreads();
    if (tid == 0)
        ((float2*)part)[blockIdx.x] =
            make_float2(ls[0] + ls[1] + ls[2] + ls[3],
                        lss[0] + lss[1] + lss[2] + lss[3]);
}

// ---------------- fused outer-product + bias + softmax + PV ------------
// one block per (b,h); 256 threads; thread pair (2c, 2c+1) owns row c.
// BN fold: out = sc * (sum p*v_raw / sum p) + sh
__global__ __launch_bounds__(256) void attn_k(
    const float* __restrict__ qv, const float* __restrict__ kparam,
    const float* __restrict__ bias, const float* __restrict__ temperature,
    const float* __restrict__ part, const float* __restrict__ gamma,
    const float* __restrict__ beta, unsigned short* __restrict__ aout)
{
    const int bh = blockIdx.x;
    const int b  = bh >> 4;
    const int h  = bh & 15;
    const int tid = threadIdx.x;

    __shared__ float ks[NCPH], vsr[NCPH], sc2[2];
    if (tid < NCPH) {
        ks[tid]  = kparam[(size_t)b * NDIM + h * NCPH + tid];
        vsr[tid] = qv[(size_t)b * (2 * NDIM) + NDIM + h * NCPH + tid];
    }
    if (tid == 0) {
        float S = 0.f, SS = 0.f;
#pragma unroll
        for (int j = 0; j < 4; j++) {
            float2 p = ((const float2*)part)[h * 4 + j];
            S += p.x; SS += p.y;
        }
        const float inv = 1.0f / (NBATCH * NCPH);
        float mean = S * inv;
        float var  = SS * inv - mean * mean;
        float sc   = gamma[h] * rsqrtf(var + 1e-5f);
        sc2[0] = sc;
        sc2[1] = beta[h] - mean * sc;
    }
    const int c = tid >> 1, half = tid & 1;
    const float qc   = qv[(size_t)b * (2 * NDIM) + h * NCPH + c];
    const float temp = temperature[h];
    __syncthreads();

    const float4* bp = (const float4*)(bias + ((size_t)bh << 14)
                                       + (size_t)c * NCPH + half * 64);
    float4 l4[16];
#pragma unroll
    for (int j = 0; j < 16; j++) l4[j] = bp[j];
    float* l = (float*)l4;

    const float* kk = ks  + half * 64;
    const float* vv = vsr + half * 64;

    float m = -1e30f;
#pragma unroll
    for (int j = 0; j < 64; j++) {
        l[j] = fmaf(qc, kk[j], l[j]) * temp;
        m = fmaxf(m, l[j]);
    }
    m = fmaxf(m, __shfl_xor(m, 1));

    float s = 0.f, o = 0.f;
#pragma unroll
    for (int j = 0; j < 64; j++) {
        float p = __expf(l[j] - m);
        s += p;
        o = fmaf(p, vv[j], o);
    }
    s += __shfl_xor(s, 1);
    o += __shfl_xor(o, 1);

    if (half == 0)
        aout[(size_t)b * NDIM + h * NCPH + c] = f2bf(fmaf(sc2[0], o / s, sc2[1]));
}

// ------------------------------ launch ---------------------------------
extern "C" void kernel_launch(void* const* d_in, const int* in_sizes, int n_in,
                              void* d_out, int out_size, void* d_ws, size_t ws_size,
                              hipStream_t stream)
{
    const float* x      = (const float*)d_in[0];
    const float* Wqv    = (const float*)d_in[1];
    const float* temp   = (const float*)d_in[2];
    const float* kparam = (const float*)d_in[3];
    const float* bias   = (const float*)d_in[4];
    const float* gamma  = (const float*)d_in[5];
    const float* beta   = (const float*)d_in[6];
    const float* Wout   = (const float*)d_in[7];
    const float* bout   = (const float*)d_in[8];
    float* out = (float*)d_out;

    char* ws = (char*)d_ws;
    unsigned short* wqv_bf  = (unsigned short*)(ws);              // 16 MiB
    unsigned short* wout_bf = (unsigned short*)(ws + 16777216);   //  8 MiB
    unsigned short* x_bf    = (unsigned short*)(ws + 25165824);   //  2 MiB
    float*          qv      = (float*)(ws + 27262976);            //  8 MiB
    unsigned short* ao_bf   = (unsigned short*)(ws + 35651584);   //  2 MiB
    float*          part    = (float*)(ws + 37748736);            // 64 float2

    cvt_all<<<13312, 256, 0, stream>>>(Wqv, Wout, x, wqv_bf, wout_bf, x_bf);

    // qv = x @ W_qv^T : M=512, N=4096, K=2048  (512 blocks = 2/CU)
    gemm_bt<64, 64, 64><<<dim3(4096 / 64, 512 / 64), 256, 0, stream>>>(
        x_bf, wqv_bf, qv, nullptr, NBATCH, 2 * NDIM, NDIM);

    bn_partial<<<64, 256, 0, stream>>>(qv, part);

    attn_k<<<NBATCH * NHEADS, 256, 0, stream>>>(
        qv, kparam, bias, temp, part, gamma, beta, ao_bf);

    // out = attn_out @ W_out^T + b_out : M=512, N=2048, K=2048 (512 blocks)
    gemm_bt<64, 32, 64><<<dim3(2048 / 32, 512 / 64), 256, 0, stream>>>(
        ao_bf, wout_bf, out, bout, NBATCH, NDIM, NDIM);
}